// Round 6
// baseline (40335.815 us; speedup 1.0000x reference)
//
#include <hip/hip_runtime.h>
#include <math.h>

#define NS 512
#define NE 2048
#define NB 64
#define NT 512

// out[c][r] = in[r][c]; rows, cols multiples of 32
__global__ __launch_bounds__(256) void transpose_k(const float* __restrict__ in,
                                                   float* __restrict__ out,
                                                   int rows, int cols) {
  __shared__ float tile[32][33];
  int c0 = blockIdx.x * 32;
  int r0 = blockIdx.y * 32;
  int tx = threadIdx.x;  // 0..31
  int ty = threadIdx.y;  // 0..7
#pragma unroll
  for (int k = 0; k < 32; k += 8) {
    tile[ty + k][tx] = in[(size_t)(r0 + ty + k) * cols + (c0 + tx)];
  }
  __syncthreads();
#pragma unroll
  for (int k = 0; k < 32; k += 8) {
    out[(size_t)(c0 + ty + k) * rows + (r0 + tx)] = tile[tx][ty + k];
  }
}

#define REP32(M) \
  M(0) M(1) M(2) M(3) M(4) M(5) M(6) M(7) \
  M(8) M(9) M(10) M(11) M(12) M(13) M(14) M(15) \
  M(16) M(17) M(18) M(19) M(20) M(21) M(22) M(23) \
  M(24) M(25) M(26) M(27) M(28) M(29) M(30) M(31)

// Forward, trans-stationary: 4 blocks per batch. Member m of group g holds
// T[i in 128m..128m+127][j] in 128 VGPRs, pinned by inline-asm anchors so the
// compiler cannot sink the loads back into the loop (R5 failure: VGPR=80,
// loads rematerialized in-loop -> 256KB/step/CU L1 traffic).
// Exchange: per-member monotonic flag cachelines (release store, no RMW),
// all-thread acquire spin, double-buffered partials by parity.
__global__ __launch_bounds__(512, 2) void viterbi_fwd(
    const int* __restrict__ obs,     // [NB][NT]
    const float* __restrict__ start, // [NS]
    const float* __restrict__ trans, // [NS][NS]
    const float* __restrict__ emT,   // [NE][NS]
    float* __restrict__ v,           // [NT][NB][NS]
    float* __restrict__ partials,    // [2][NB][4][NS]
    int* __restrict__ flags)         // [NB][4][32], zeroed before launch
{
  const int g = blockIdx.x & 63;   // batch / group
  const int m = blockIdx.x >> 6;   // member 0..3 (same XCD residue within group)
  const int j = threadIdx.x;       // 0..511
  const int i0 = m * 128;

  __shared__ __align__(16) float vcur[NS];
  __shared__ int obs_s[NT];

  obs_s[j] = obs[g * NT + j];

  // T[i0 + 4c + r][j] -> 4 named scalars per c, anchored into VGPRs.
#define LOADT(c) \
  float ta##c = trans[(size_t)(i0 + (c) * 4 + 0) * NS + j]; \
  float tb##c = trans[(size_t)(i0 + (c) * 4 + 1) * NS + j]; \
  float tc##c = trans[(size_t)(i0 + (c) * 4 + 2) * NS + j]; \
  float td##c = trans[(size_t)(i0 + (c) * 4 + 3) * NS + j]; \
  asm volatile("" : "+v"(ta##c), "+v"(tb##c), "+v"(tc##c), "+v"(td##c));
  REP32(LOADT)
#undef LOADT

  __syncthreads();
  // t = 0 (every member computes identically; member 0 checkpoints, deferred)
  float vj = start[j] + emT[(size_t)obs_s[0] * NS + j];
  vcur[j] = vj;
  float vprev = vj;  // checkpoint of step t-1, stored at top of step t
  __syncthreads();

  float e_next = emT[(size_t)obs_s[1] * NS + j];

  int* flag_me = flags + (g * 4 + m) * 32;
  int* flag_r1 = flags + (g * 4 + ((m + 1) & 3)) * 32;
  int* flag_r2 = flags + (g * 4 + ((m + 2) & 3)) * 32;
  int* flag_r3 = flags + (g * 4 + ((m + 3) & 3)) * 32;

  for (int t = 1; t < NT; ++t) {
    // deferred checkpoint of t-1: store overlaps this step's compute
    if (m == 0) v[((size_t)(t - 1) * NB + g) * NS + j] = vprev;

    float e_cur = e_next;
    if (t + 1 < NT) e_next = emT[(size_t)obs_s[t + 1] * NS + j];

    // partial max over my 128-row i-slice (register trans + LDS broadcast vcur)
    float m0 = -INFINITY, m1 = -INFINITY;
    const float4* vc4 = reinterpret_cast<const float4*>(vcur + i0);
#define STEPC(c) \
    { float4 vv = vc4[c]; \
      m0 = fmaxf(m0, fmaxf(vv.x + ta##c, vv.y + tb##c)); \
      m1 = fmaxf(m1, fmaxf(vv.z + tc##c, vv.w + td##c)); }
    REP32(STEPC)
#undef STEPC
    float pm = fmaxf(m0, m1);

    // publish my partial (write-through to coherence point)
    float* pbase = partials + (((size_t)(t & 1) * NB + g) * 4) * NS;
    __hip_atomic_store(pbase + m * NS + j, pm, __ATOMIC_RELAXED, __HIP_MEMORY_SCOPE_AGENT);
    __syncthreads();  // all vcur reads done; all partial stores drained (vmcnt 0)

    if (j == 0) {
      __hip_atomic_store(flag_me, t, __ATOMIC_RELEASE, __HIP_MEMORY_SCOPE_AGENT);
    }
    // all threads spin; same-address loads coalesce per wave
    for (;;) {
      int f1 = __hip_atomic_load(flag_r1, __ATOMIC_ACQUIRE, __HIP_MEMORY_SCOPE_AGENT);
      int f2 = __hip_atomic_load(flag_r2, __ATOMIC_ACQUIRE, __HIP_MEMORY_SCOPE_AGENT);
      int f3 = __hip_atomic_load(flag_r3, __ATOMIC_ACQUIRE, __HIP_MEMORY_SCOPE_AGENT);
      if (f1 >= t && f2 >= t && f3 >= t) break;
      __builtin_amdgcn_s_sleep(1);
    }

    float q1 = __hip_atomic_load(pbase + (((m + 1) & 3) * NS) + j, __ATOMIC_RELAXED, __HIP_MEMORY_SCOPE_AGENT);
    float q2 = __hip_atomic_load(pbase + (((m + 2) & 3) * NS) + j, __ATOMIC_RELAXED, __HIP_MEMORY_SCOPE_AGENT);
    float q3 = __hip_atomic_load(pbase + (((m + 3) & 3) * NS) + j, __ATOMIC_RELAXED, __HIP_MEMORY_SCOPE_AGENT);
    float vn = fmaxf(fmaxf(pm, q1), fmaxf(q2, q3)) + e_cur;

    vcur[j] = vn;  // old-vcur reads all happened before the mid barrier
    vprev = vn;
    __syncthreads();
  }
  if (m == 0) v[((size_t)(NT - 1) * NB + g) * NS + j] = vprev;
}

// Backtrace: one wave per batch; recompute argmax with exact first-wins ties.
__global__ __launch_bounds__(64) void viterbi_bt(
    const float* __restrict__ v,      // [NT][NB][NS]
    const float* __restrict__ transT, // [NS][NS], transT[j][i] = trans[i][j]
    int* __restrict__ path)           // [NB][NT] int32
{
  const int b = blockIdx.x;
  const int lane = threadIdx.x;

  const float4* vrow = reinterpret_cast<const float4*>(v + ((size_t)(NT - 1) * NB + b) * NS);
  float val = -INFINITY;
  int idx = 0;
#pragma unroll
  for (int w = 0; w < 2; ++w) {
    float4 a = vrow[lane + 64 * w];
    int base = 4 * (lane + 64 * w);
    if (a.x > val) { val = a.x; idx = base + 0; }
    if (a.y > val) { val = a.y; idx = base + 1; }
    if (a.z > val) { val = a.z; idx = base + 2; }
    if (a.w > val) { val = a.w; idx = base + 3; }
  }
#pragma unroll
  for (int off = 32; off; off >>= 1) {
    float v2 = __shfl_down(val, off);
    int i2 = __shfl_down(idx, off);
    if (v2 > val || (v2 == val && i2 < idx)) { val = v2; idx = i2; }
  }
  int state = __shfl(idx, 0);
  if (lane == 0) path[b * NT + (NT - 1)] = state;

  float4 vp0, vp1;
  {
    const float4* vp = reinterpret_cast<const float4*>(v + ((size_t)(NT - 2) * NB + b) * NS);
    vp0 = vp[lane];
    vp1 = vp[lane + 64];
  }

  for (int t = NT - 1; t >= 1; --t) {
    float4 np0, np1;
    if (t >= 2) {
      const float4* vp = reinterpret_cast<const float4*>(v + ((size_t)(t - 2) * NB + b) * NS);
      np0 = vp[lane];
      np1 = vp[lane + 64];
    }
    const float4* tr = reinterpret_cast<const float4*>(transT + (size_t)state * NS);
    float4 t0 = tr[lane];
    float4 t1 = tr[lane + 64];

    float val2 = -INFINITY;
    int idx2 = 0;
    {
      float s0 = vp0.x + t0.x, s1 = vp0.y + t0.y, s2 = vp0.z + t0.z, s3 = vp0.w + t0.w;
      int base = 4 * lane;
      if (s0 > val2) { val2 = s0; idx2 = base + 0; }
      if (s1 > val2) { val2 = s1; idx2 = base + 1; }
      if (s2 > val2) { val2 = s2; idx2 = base + 2; }
      if (s3 > val2) { val2 = s3; idx2 = base + 3; }
    }
    {
      float s0 = vp1.x + t1.x, s1 = vp1.y + t1.y, s2 = vp1.z + t1.z, s3 = vp1.w + t1.w;
      int base = 4 * (lane + 64);
      if (s0 > val2) { val2 = s0; idx2 = base + 0; }
      if (s1 > val2) { val2 = s1; idx2 = base + 1; }
      if (s2 > val2) { val2 = s2; idx2 = base + 2; }
      if (s3 > val2) { val2 = s3; idx2 = base + 3; }
    }
#pragma unroll
    for (int off = 32; off; off >>= 1) {
      float v2 = __shfl_down(val2, off);
      int i2 = __shfl_down(idx2, off);
      if (v2 > val2 || (v2 == val2 && i2 < idx2)) { val2 = v2; idx2 = i2; }
    }
    state = __shfl(idx2, 0);
    if (lane == 0) path[b * NT + (t - 1)] = state;
    vp0 = np0;
    vp1 = np1;
  }
}

extern "C" void kernel_launch(void* const* d_in, const int* in_sizes, int n_in,
                              void* d_out, int out_size, void* d_ws, size_t ws_size,
                              hipStream_t stream) {
  const int* obs = (const int*)d_in[0];       // [64][512]
  const float* start = (const float*)d_in[1]; // [512]
  const float* trans = (const float*)d_in[2]; // [512][512]
  const float* emis = (const float*)d_in[3];  // [512][2048]
  int* path = (int*)d_out;                    // [64][512] int32

  char* ws = (char*)d_ws;
  float* emT = (float*)ws;                           // [2048][512] = 4 MB
  float* transT = (float*)(ws + (4ull << 20));       // [512][512]  = 1 MB
  float* v = (float*)(ws + (5ull << 20));            // [512][64][512] = 64 MB
  float* partials = (float*)(ws + (69ull << 20));    // [2][64][4][512] = 1 MB
  int* flags = (int*)(ws + (70ull << 20));           // [64][4][32] = 32 KB

  hipMemsetAsync(flags, 0, NB * 4 * 32 * sizeof(int), stream);

  dim3 tb(32, 8);
  transpose_k<<<dim3(NE / 32, NS / 32), tb, 0, stream>>>(emis, emT, NS, NE);
  transpose_k<<<dim3(NS / 32, NS / 32), tb, 0, stream>>>(trans, transT, NS, NS);
  viterbi_fwd<<<NB * 4, 512, 0, stream>>>(obs, start, trans, emT, v, partials, flags);
  viterbi_bt<<<NB, 64, 0, stream>>>(v, transT, path);
}

// Round 7
// 3320.823 us; speedup vs baseline: 12.1463x; 12.1463x over previous
//
#include <hip/hip_runtime.h>
#include <math.h>

#define NS 512
#define NE 2048
#define NB 64
#define NT 512

// out[c][r] = in[r][c]; rows, cols multiples of 32
__global__ __launch_bounds__(256) void transpose_k(const float* __restrict__ in,
                                                   float* __restrict__ out,
                                                   int rows, int cols) {
  __shared__ float tile[32][33];
  int c0 = blockIdx.x * 32;
  int r0 = blockIdx.y * 32;
  int tx = threadIdx.x;  // 0..31
  int ty = threadIdx.y;  // 0..7
#pragma unroll
  for (int k = 0; k < 32; k += 8) {
    tile[ty + k][tx] = in[(size_t)(r0 + ty + k) * cols + (c0 + tx)];
  }
  __syncthreads();
#pragma unroll
  for (int k = 0; k < 32; k += 8) {
    out[(size_t)(c0 + ty + k) * rows + (r0 + tx)] = tile[tx][ty + k];
  }
}

// Forward, trans-stationary-ish: 4 blocks per batch. Member m of group g covers
// i in [128m, 128m+128): 28 rows staged once in LDS, 100 rows streamed from L2
// per step (register residency refused by compiler 3x: R3/R4/R6, VGPR stuck 64-80).
// Exchange per step: agent-scope partial store -> barrier (vmcnt drain) ->
// j==0: release flag store, RELAXED spin on 3 remote flag lines (+1 acquire) ->
// barrier -> agent-scope partial loads. Partials double-buffered by parity;
// flags monotonic (t), zeroed before launch.
__global__ __launch_bounds__(512, 2) void viterbi_fwd(
    const int* __restrict__ obs,     // [NB][NT]
    const float* __restrict__ start, // [NS]
    const float* __restrict__ trans, // [NS][NS]
    const float* __restrict__ emT,   // [NE][NS]
    float* __restrict__ v,           // [NT][NB][NS]
    float* __restrict__ partials,    // [2][NB][4][NS]
    int* __restrict__ flags)         // [NB][4][32], zeroed before launch
{
  const int g = blockIdx.x & 63;   // batch / group
  const int m = blockIdx.x >> 6;   // member 0..3
  const int j = threadIdx.x;       // 0..511
  const int i0 = m * 128;

  __shared__ __align__(16) float vcur[NS];
  __shared__ __align__(16) float tl[28 * NS];  // 57344 B staged trans rows
  __shared__ int obs_s[NT];

  obs_s[j] = obs[g * NT + j];
#pragma unroll
  for (int r = 0; r < 28; ++r) {
    tl[r * NS + j] = trans[(size_t)(i0 + r) * NS + j];
  }

  // t = 0 (every member computes identically; member 0 checkpoints, deferred)
  float vj = start[j] + emT[(size_t)obs[g * NT] * NS + j];
  vcur[j] = vj;
  float vprev = vj;
  __syncthreads();

  float e_next = emT[(size_t)obs_s[1] * NS + j];

  int* flag_me = flags + (g * 4 + m) * 32;
  int* flag_r1 = flags + (g * 4 + ((m + 1) & 3)) * 32;
  int* flag_r2 = flags + (g * 4 + ((m + 2) & 3)) * 32;
  int* flag_r3 = flags + (g * 4 + ((m + 3) & 3)) * 32;

  for (int t = 1; t < NT; ++t) {
    // deferred checkpoint of t-1: m==0's store drains under this step's compute
    if (m == 0) v[((size_t)(t - 1) * NB + g) * NS + j] = vprev;

    float e_cur = e_next;
    if (t + 1 < NT) e_next = emT[(size_t)obs_s[t + 1] * NS + j];

    // partial max over my 128-row i-slice
    float m0 = -INFINITY, m1 = -INFINITY;
    const float4* vc4 = reinterpret_cast<const float4*>(vcur + i0);
#pragma unroll
    for (int c = 0; c < 7; ++c) {  // rows 0..27 of my slice: LDS
      float4 vv = vc4[c];
      m0 = fmaxf(m0, fmaxf(vv.x + tl[(4 * c + 0) * NS + j],
                           vv.y + tl[(4 * c + 1) * NS + j]));
      m1 = fmaxf(m1, fmaxf(vv.z + tl[(4 * c + 2) * NS + j],
                           vv.w + tl[(4 * c + 3) * NS + j]));
    }
#pragma unroll
    for (int c = 7; c < 32; ++c) {  // rows 28..127: streamed from L2
      float4 vv = vc4[c];
      const float* p = trans + (size_t)(i0 + 4 * c) * NS + j;
      m0 = fmaxf(m0, fmaxf(vv.x + p[0 * NS], vv.y + p[1 * NS]));
      m1 = fmaxf(m1, fmaxf(vv.z + p[2 * NS], vv.w + p[3 * NS]));
    }
    float pm = fmaxf(m0, m1);

    // publish my partial (agent scope -> coherence point)
    float* pbase = partials + (((size_t)(t & 1) * NB + g) * 4) * NS;
    __hip_atomic_store(pbase + m * NS + j, pm, __ATOMIC_RELAXED, __HIP_MEMORY_SCOPE_AGENT);
    __syncthreads();  // all vcur reads done; all partial stores drained (vmcnt 0)

    if (j == 0) {
      __hip_atomic_store(flag_me, t, __ATOMIC_RELEASE, __HIP_MEMORY_SCOPE_AGENT);
      while (__hip_atomic_load(flag_r1, __ATOMIC_RELAXED, __HIP_MEMORY_SCOPE_AGENT) < t ||
             __hip_atomic_load(flag_r2, __ATOMIC_RELAXED, __HIP_MEMORY_SCOPE_AGENT) < t ||
             __hip_atomic_load(flag_r3, __ATOMIC_RELAXED, __HIP_MEMORY_SCOPE_AGENT) < t) {
        __builtin_amdgcn_s_sleep(2);
      }
      (void)__hip_atomic_load(flag_r1, __ATOMIC_ACQUIRE, __HIP_MEMORY_SCOPE_AGENT);
    }
    __syncthreads();  // flags observed -> all 4 partials at coherence point

    float q1 = __hip_atomic_load(pbase + (((m + 1) & 3) * NS) + j, __ATOMIC_RELAXED, __HIP_MEMORY_SCOPE_AGENT);
    float q2 = __hip_atomic_load(pbase + (((m + 2) & 3) * NS) + j, __ATOMIC_RELAXED, __HIP_MEMORY_SCOPE_AGENT);
    float q3 = __hip_atomic_load(pbase + (((m + 3) & 3) * NS) + j, __ATOMIC_RELAXED, __HIP_MEMORY_SCOPE_AGENT);
    float vn = fmaxf(fmaxf(pm, q1), fmaxf(q2, q3)) + e_cur;

    vcur[j] = vn;  // old-vcur reads all happened before the mid barrier
    vprev = vn;
    __syncthreads();
  }
  if (m == 0) v[((size_t)(NT - 1) * NB + g) * NS + j] = vprev;
}

// Backtrace: one wave per batch; recompute argmax with exact first-wins ties.
__global__ __launch_bounds__(64) void viterbi_bt(
    const float* __restrict__ v,      // [NT][NB][NS]
    const float* __restrict__ transT, // [NS][NS], transT[j][i] = trans[i][j]
    int* __restrict__ path)           // [NB][NT] int32
{
  const int b = blockIdx.x;
  const int lane = threadIdx.x;

  const float4* vrow = reinterpret_cast<const float4*>(v + ((size_t)(NT - 1) * NB + b) * NS);
  float val = -INFINITY;
  int idx = 0;
#pragma unroll
  for (int w = 0; w < 2; ++w) {
    float4 a = vrow[lane + 64 * w];
    int base = 4 * (lane + 64 * w);
    if (a.x > val) { val = a.x; idx = base + 0; }
    if (a.y > val) { val = a.y; idx = base + 1; }
    if (a.z > val) { val = a.z; idx = base + 2; }
    if (a.w > val) { val = a.w; idx = base + 3; }
  }
#pragma unroll
  for (int off = 32; off; off >>= 1) {
    float v2 = __shfl_down(val, off);
    int i2 = __shfl_down(idx, off);
    if (v2 > val || (v2 == val && i2 < idx)) { val = v2; idx = i2; }
  }
  int state = __shfl(idx, 0);
  if (lane == 0) path[b * NT + (NT - 1)] = state;

  float4 vp0, vp1;
  {
    const float4* vp = reinterpret_cast<const float4*>(v + ((size_t)(NT - 2) * NB + b) * NS);
    vp0 = vp[lane];
    vp1 = vp[lane + 64];
  }

  for (int t = NT - 1; t >= 1; --t) {
    float4 np0, np1;
    if (t >= 2) {
      const float4* vp = reinterpret_cast<const float4*>(v + ((size_t)(t - 2) * NB + b) * NS);
      np0 = vp[lane];
      np1 = vp[lane + 64];
    }
    const float4* tr = reinterpret_cast<const float4*>(transT + (size_t)state * NS);
    float4 t0 = tr[lane];
    float4 t1 = tr[lane + 64];

    float val2 = -INFINITY;
    int idx2 = 0;
    {
      float s0 = vp0.x + t0.x, s1 = vp0.y + t0.y, s2 = vp0.z + t0.z, s3 = vp0.w + t0.w;
      int base = 4 * lane;
      if (s0 > val2) { val2 = s0; idx2 = base + 0; }
      if (s1 > val2) { val2 = s1; idx2 = base + 1; }
      if (s2 > val2) { val2 = s2; idx2 = base + 2; }
      if (s3 > val2) { val2 = s3; idx2 = base + 3; }
    }
    {
      float s0 = vp1.x + t1.x, s1 = vp1.y + t1.y, s2 = vp1.z + t1.z, s3 = vp1.w + t1.w;
      int base = 4 * (lane + 64);
      if (s0 > val2) { val2 = s0; idx2 = base + 0; }
      if (s1 > val2) { val2 = s1; idx2 = base + 1; }
      if (s2 > val2) { val2 = s2; idx2 = base + 2; }
      if (s3 > val2) { val2 = s3; idx2 = base + 3; }
    }
#pragma unroll
    for (int off = 32; off; off >>= 1) {
      float v2 = __shfl_down(val2, off);
      int i2 = __shfl_down(idx2, off);
      if (v2 > val2 || (v2 == val2 && i2 < idx2)) { val2 = v2; idx2 = i2; }
    }
    state = __shfl(idx2, 0);
    if (lane == 0) path[b * NT + (t - 1)] = state;
    vp0 = np0;
    vp1 = np1;
  }
}

extern "C" void kernel_launch(void* const* d_in, const int* in_sizes, int n_in,
                              void* d_out, int out_size, void* d_ws, size_t ws_size,
                              hipStream_t stream) {
  const int* obs = (const int*)d_in[0];       // [64][512]
  const float* start = (const float*)d_in[1]; // [512]
  const float* trans = (const float*)d_in[2]; // [512][512]
  const float* emis = (const float*)d_in[3];  // [512][2048]
  int* path = (int*)d_out;                    // [64][512] int32

  char* ws = (char*)d_ws;
  float* emT = (float*)ws;                           // [2048][512] = 4 MB
  float* transT = (float*)(ws + (4ull << 20));       // [512][512]  = 1 MB
  float* v = (float*)(ws + (5ull << 20));            // [512][64][512] = 64 MB
  float* partials = (float*)(ws + (69ull << 20));    // [2][64][4][512] = 1 MB
  int* flags = (int*)(ws + (70ull << 20));           // [64][4][32] = 32 KB

  hipMemsetAsync(flags, 0, NB * 4 * 32 * sizeof(int), stream);

  dim3 tb(32, 8);
  transpose_k<<<dim3(NE / 32, NS / 32), tb, 0, stream>>>(emis, emT, NS, NE);
  transpose_k<<<dim3(NS / 32, NS / 32), tb, 0, stream>>>(trans, transT, NS, NS);
  viterbi_fwd<<<NB * 4, 512, 0, stream>>>(obs, start, trans, emT, v, partials, flags);
  viterbi_bt<<<NB, 64, 0, stream>>>(v, transT, path);
}